// Round 11
// baseline (198.672 us; speedup 1.0000x reference)
//
#include <hip/hip_runtime.h>

// QuantizedActorMLP: x(1M,17) -> quant -> L1(17->64)+quantact -> L2(64->64)+quantact -> L3(64->6)
// Integer-exact bf16 MFMA (ints |n|<=127 exact in bf16, sums < 2^24 exact in fp32 acc).
// R20: test the LDS-DMA-path hypothesis. Cycle budget shows R13's wall is the per-round
//      vmcnt wait (~11us/round = 17.8MB @ ~1.9TB/s service). Every ~1.9TB/s kernel here
//      staged via global_load_lds; every faster regime (qquant ~4TB/s, copy 6.3TB/s,
//      spill traffic 2.4TB/s) used plain register loads. R17/R18's register-staging test
//      was invalidated by allocator occupancy-greed (launch_bounds only sets MIN waves).
//      Fix: __attribute__((amdgpu_waves_per_eu(4,4))) pins waves/EU to exactly 4 ->
//      128-VGPR budget, no incentive to spill the 17-VGPR staging batch (need ~105).
//  Structure = R13 verbatim except staging: global -> 17 VGPR/lane (4x dwordx4 + 1x
//  dword, dense coalesced) -> ds_write -> single 1088-dw LDS buffer/wave (no double
//  buffer needed; the registers ARE the in-flight buffer, depth-1 as in R13).
//  Bias LDS tables (R15/R16-verified) keep base VGPR ~88. Same in-flight bytes, same
//  tile decomposition, same MFMA core/funnel stores -> pure path A/B vs R13.
//  Falsifiers: WRITE_SIZE > 30MB (spill) or dur ~51us (path-independent cap) -> R13
//  is the structural plateau.

typedef __attribute__((ext_vector_type(8))) short short8;    // MFMA A/B frag (8 bf16)
typedef __attribute__((ext_vector_type(4))) float floatx4;   // MFMA C/D frag
typedef __attribute__((ext_vector_type(4))) unsigned int uint4v;
typedef unsigned int uint;

__device__ __forceinline__ uint f32bits(float v) { union { float f; uint u; } c; c.f = v; return c.u; }
__device__ __forceinline__ short bf16i(float v) { return (short)(f32bits(v) >> 16); }
// pack two integer-valued f32 -> two bf16 in one uint (low = z0): one v_perm_b32
__device__ __forceinline__ uint pack2(float z0, float z1) {
  return __builtin_amdgcn_perm(f32bits(z1), f32bits(z0), 0x07060302u);
}
// round-to-nearest-even integer clamped to [-127,127]: v_med3 + v_rndne
__device__ __forceinline__ float qclamp(float v) {
  return __builtin_rintf(__builtin_amdgcn_fmed3f(v, -127.f, 127.f));
}
__device__ __forceinline__ int imin(int a, int b) { return a < b ? a : b; }

__global__ void __launch_bounds__(256)
__attribute__((amdgpu_waves_per_eu(4, 4)))
qmlp_fused(
    const float* __restrict__ x,
    const float* __restrict__ W1, const float* __restrict__ b1,
    const float* __restrict__ W2, const float* __restrict__ b2,
    const float* __restrict__ W3, const float* __restrict__ b3,
    float* __restrict__ out, int B)
{
  constexpr float QMAXF = 127.0f;
  constexpr float SCALE = 1.33f;
  const float step  = SCALE / QMAXF;
  const float istep = QMAXF / SCALE;

  // One shared pool, two lifetimes:
  //  preamble: wraw1[0..1088) wraw2[1088..5248) wraw3[5248..5638) redv[5638..5650)
  //  main loop: per-wave single x buffer [w*1088, +1088)  (4352 dw, overlays wraw1/2)
  //  persistent: bias tables b1t[5650..5714) b2t[5714..5778) b3t[5778..5794)
  __shared__ __align__(16) float smem[5794];
  float* wraw1 = smem;            // W1 raw, pitch 17
  float* wraw2 = smem + 1088;     // W2 raw, pitch 65 (pad kills gather conflicts)
  float* wraw3 = smem + 5248;     // W3 raw, pitch 65
  float* redv  = smem + 5638;     // per-wave (m1,m2,m3)
  float* b1t   = smem + 5650;     // b1[n]*istep
  float* b2t   = smem + 5714;     // b2[n]*istep
  float* b3t   = smem + 5778;     // b3[n] (n<6) else 0

  const int tid  = threadIdx.x;
  const int lane = tid & 63;
  const int bi   = lane & 15;
  const int q    = lane >> 4;
  const int w    = tid >> 6;

  // ---- coalesced staging of raw weights into LDS, max-abs fused into the load ----
  float m1 = 0.f, m2 = 0.f, m3 = 0.f;
  for (int i = tid; i < 272; i += 256) {                       // W1: 1088 floats = 272 float4
    float4 v = ((const float4*)W1)[i];
    ((float4*)wraw1)[i] = v;
    m1 = fmaxf(m1, fmaxf(fmaxf(fabsf(v.x), fabsf(v.y)), fmaxf(fabsf(v.z), fabsf(v.w))));
  }
  for (int i = tid; i < 1024; i += 256) {                      // W2: 4096 floats = 1024 float4
    float4 v = ((const float4*)W2)[i];
    int r = i >> 4, c0 = (i & 15) * 4;                         // no float4 crosses a 64-row
    float* dst = &wraw2[r * 65 + c0];
    dst[0] = v.x; dst[1] = v.y; dst[2] = v.z; dst[3] = v.w;
    m2 = fmaxf(m2, fmaxf(fmaxf(fabsf(v.x), fabsf(v.y)), fmaxf(fabsf(v.z), fabsf(v.w))));
  }
  for (int i = tid; i < 96; i += 256) {                        // W3: 384 floats = 96 float4
    float4 v = ((const float4*)W3)[i];
    int r = i >> 4, c0 = (i & 15) * 4;
    float* dst = &wraw3[r * 65 + c0];
    dst[0] = v.x; dst[1] = v.y; dst[2] = v.z; dst[3] = v.w;
    m3 = fmaxf(m3, fmaxf(fmaxf(fabsf(v.x), fabsf(v.y)), fmaxf(fabsf(v.z), fabsf(v.w))));
  }
  // bias tables (persistent region, disjoint from wraw* and x buffer): written once
  if (tid < 64) {
    b1t[tid] = b1[tid] * istep;
    b2t[tid] = b2[tid] * istep;
  }
  if (tid < 16) b3t[tid] = (tid < 6) ? b3[tid] : 0.f;

  #pragma unroll
  for (int off = 32; off > 0; off >>= 1) {
    m1 = fmaxf(m1, __shfl_down(m1, off));
    m2 = fmaxf(m2, __shfl_down(m2, off));
    m3 = fmaxf(m3, __shfl_down(m3, off));
  }
  if (lane == 0) {
    redv[w * 3 + 0] = m1; redv[w * 3 + 1] = m2; redv[w * 3 + 2] = m3;
  }
  __syncthreads();                 // barrier 1: publishes redv + wraw1/2/3 + bias tables
  float s1 = 0.f, s2 = 0.f, s3 = 0.f;
  #pragma unroll
  for (int i = 0; i < 4; ++i) {
    s1 = fmaxf(s1, redv[i * 3 + 0]);
    s2 = fmaxf(s2, redv[i * 3 + 1]);
    s3 = fmaxf(s3, redv[i * 3 + 2]);
  }
  s1 /= QMAXF; s2 /= QMAXF; s3 /= QMAXF;
  const float rs1 = 1.0f / s1, rs2 = 1.0f / s2, rs3 = 1.0f / s3;

  // ---- weight fragments (integer-valued bf16) from LDS (reciprocal-mul quant) ----
  short8 w1f[4];
  #pragma unroll
  for (int t = 0; t < 4; ++t) {
    #pragma unroll
    for (int j = 0; j < 8; ++j) {
      int k = 8 * q + j;
      float wv = (k < 17) ? wraw1[(16 * t + bi) * 17 + k] : 0.f;
      float wi = fminf(fmaxf(rintf(wv * rs1), -QMAXF), QMAXF);
      w1f[t][j] = bf16i(wi);
    }
  }
  // K-permutation: eta = 32s + 16(j>>2) + 4q + (j&3) so layer-L C/D regs feed layer-(L+1) B-frags.
  short8 w2f[4][2];
  #pragma unroll
  for (int t = 0; t < 4; ++t) {
    #pragma unroll
    for (int s = 0; s < 2; ++s) {
      #pragma unroll
      for (int j = 0; j < 8; ++j) {
        int eta = 32 * s + 16 * (j >> 2) + 4 * q + (j & 3);
        float wv = wraw2[(16 * t + bi) * 65 + eta];
        float wi = fminf(fmaxf(rintf(wv * rs2), -QMAXF), QMAXF);
        w2f[t][s][j] = bf16i(wi);
      }
    }
  }
  short8 w3f[2];
  #pragma unroll
  for (int s = 0; s < 2; ++s) {
    #pragma unroll
    for (int j = 0; j < 8; ++j) {
      int eta = 32 * s + 16 * (j >> 2) + 4 * q + (j & 3);
      float wv = (bi < 6) ? wraw3[bi * 65 + eta] : 0.f;
      float wi = fminf(fmaxf(rintf(wv * rs3), -QMAXF), QMAXF);
      w3f[s][j] = bf16i(wi);
    }
  }

  __syncthreads();                 // barrier 2: weight LDS dead -> safe to reuse for x buffer

  const float g1 = (s1 * step) * istep;
  const float g2 = (s2 * step) * istep;
  const float sc3 = s3 * step;

  // ---- scalarized work decomposition over 4-tile supertiles ----
  const int ntiles = B >> 4;                                   // 65536
  const int nSup   = ntiles >> 2;                              // 16384 supertiles (64 rows each)
  const int nw     = (int)(gridDim.x << 2);                    // 4096 waves
  const int wid    = __builtin_amdgcn_readfirstlane((int)(blockIdx.x << 2) + w);
  const int nIter  = (nSup + nw - 1) / nw;                     // 4
  const int lastS  = nSup - 1;

  float* xb = smem + w * 1088;                                 // ONE 1088-dword buffer/wave

  const int lane4 = lane * 4;                                  // dword offsets
  const int fbase = bi * 17 + 8 * q;                           // frag base (q<2)
  const int fb2   = bi * 17 + 16;                              // q==2 single element

  // ---- register batch: one supertile = 17 VGPRs/lane, dense coalesced loads ----
  struct Batch { float4 v[4]; float t; };
  auto loadB = [&](int s, Batch& b) {
    const float* tp = x + (size_t)s * 1088;
    #pragma unroll
    for (int c = 0; c < 4; ++c)
      b.v[c] = *(const float4*)(tp + 256 * c + lane4);         // 4x global_load_dwordx4
    b.t = tp[1024 + lane];                                     // 1x global_load_dword
  };
  auto writeB = [&](const Batch& b) {                          // redistribute via LDS
    #pragma unroll
    for (int c = 0; c < 4; ++c)
      *(float4*)(xb + 256 * c + lane4) = b.v[c];               // linear ds_write_b128
    xb[1024 + lane] = b.t;                                     // ds_write_b32, exact
  };

  const floatx4 zero4 = {0.f, 0.f, 0.f, 0.f};

  // ---- prologue: fill the register batch (depth-1, same in-flight bytes as R13) ----
  Batch A;
  loadB(imin(wid, lastS), A);

  #pragma unroll 1
  for (int it = 0; it < nIter; ++it) {
    const int gs = imin(wid + it * nw, lastS);

    // commit batch to LDS (compiler emits precise vmcnt for its 5 loads), then refill
    // registers with the NEXT supertile -- loads land during this iteration's compute.
    writeB(A);
    if (it + 1 < nIter) loadB(imin(wid + (it + 1) * nw, lastS), A);
    asm volatile("" ::: "memory");                             // pin ds_write -> gather order

    #pragma unroll 1
    for (int k = 0; k < 4; ++k) {
      float* tb = xb + k * 272;

      // fragment gather from LDS (stride-17-dword: max 2-way bank alias = free)
      float xr[8];
      if (q < 2) {
        #pragma unroll
        for (int j = 0; j < 8; ++j) xr[j] = tb[fbase + j];
      } else if (q == 2) {
        xr[0] = tb[fb2];
        #pragma unroll
        for (int j = 1; j < 8; ++j) xr[j] = 0.f;
      } else {
        #pragma unroll
        for (int j = 0; j < 8; ++j) xr[j] = 0.f;
      }

      // input quant -> B-frag: lane holds Xq[row=bi][k=8q+j]
      uint4v ap;
      #pragma unroll
      for (int jp = 0; jp < 4; ++jp)
        ap[jp] = pack2(qclamp(xr[2 * jp] * istep), qclamp(xr[2 * jp + 1] * istep));
      short8 af = __builtin_bit_cast(short8, ap);

      // L1
      floatx4 c1[4];
      #pragma unroll
      for (int t = 0; t < 4; ++t)
        c1[t] = __builtin_amdgcn_mfma_f32_16x16x32_bf16(w1f[t], af, zero4, 0, 0, 0);

      uint4v h1u[2];
      #pragma unroll
      for (int t = 0; t < 4; ++t) {
        float4 bb = *(const float4*)(b1t + 16 * t + 4 * q);    // broadcast ds_read_b128
        float z0 = qclamp(fmaf(c1[t][0], g1, bb.x));
        float z1 = qclamp(fmaf(c1[t][1], g1, bb.y));
        float z2 = qclamp(fmaf(c1[t][2], g1, bb.z));
        float z3 = qclamp(fmaf(c1[t][3], g1, bb.w));
        h1u[t >> 1][(t & 1) * 2 + 0] = pack2(z0, z1);
        h1u[t >> 1][(t & 1) * 2 + 1] = pack2(z2, z3);
      }
      short8 h1a = __builtin_bit_cast(short8, h1u[0]);
      short8 h1b = __builtin_bit_cast(short8, h1u[1]);

      // L2 (K=64)
      floatx4 c2[4];
      #pragma unroll
      for (int t = 0; t < 4; ++t) {
        c2[t] = __builtin_amdgcn_mfma_f32_16x16x32_bf16(w2f[t][0], h1a, zero4, 0, 0, 0);
        c2[t] = __builtin_amdgcn_mfma_f32_16x16x32_bf16(w2f[t][1], h1b, c2[t], 0, 0, 0);
      }

      uint4v h2u[2];
      #pragma unroll
      for (int t = 0; t < 4; ++t) {
        float4 bb = *(const float4*)(b2t + 16 * t + 4 * q);
        float z0 = qclamp(fmaf(c2[t][0], g2, bb.x));
        float z1 = qclamp(fmaf(c2[t][1], g2, bb.y));
        float z2 = qclamp(fmaf(c2[t][2], g2, bb.z));
        float z3 = qclamp(fmaf(c2[t][3], g2, bb.w));
        h2u[t >> 1][(t & 1) * 2 + 0] = pack2(z0, z1);
        h2u[t >> 1][(t & 1) * 2 + 1] = pack2(z2, z3);
      }
      short8 h2a = __builtin_bit_cast(short8, h2u[0]);
      short8 h2b = __builtin_bit_cast(short8, h2u[1]);

      // L3
      floatx4 c3;
      c3 = __builtin_amdgcn_mfma_f32_16x16x32_bf16(w3f[0], h2a, zero4, 0, 0, 0);
      c3 = __builtin_amdgcn_mfma_f32_16x16x32_bf16(w3f[1], h2b, c3, 0, 0, 0);

      float4 b3v = *(const float4*)(b3t + 4 * q);
      float o0 = fmaf(c3[0], sc3, b3v.x);
      float o1 = fmaf(c3[1], sc3, b3v.y);
      float o2 = fmaf(c3[2], sc3, b3v.z);
      float o3 = fmaf(c3[3], sc3, b3v.w);

      // stage tile-k output IN-PLACE at xb[k*96]: every write lands on input already
      // consumed in program order (verified R13/R17). ds_write_b64, 24B stride.
      float* ob = xb + k * 96;
      if (q == 0) {
        *(float2*)(ob + bi * 6)     = make_float2(o0, o1);
        *(float2*)(ob + bi * 6 + 2) = make_float2(o2, o3);
      } else if (q == 1) {
        *(float2*)(ob + bi * 6 + 4) = make_float2(o0, o1);
      }
    }

    asm volatile("" ::: "memory");                             // pin LDS write->read order
    // batched store of 64 rows x 6 = 384 dw = 1536B contiguous: 2 dwordx4 stores
    {
      float4 v0 = *(const float4*)(xb + lane4);                // dw 0..255
      *(float4*)(out + (size_t)gs * 384 + lane4) = v0;
      if (lane < 32) {
        float4 v1 = *(const float4*)(xb + 256 + lane4);        // dw 256..383
        *(float4*)(out + (size_t)gs * 384 + 256 + lane4) = v1;
      }
    }
    asm volatile("" ::: "memory");                             // next writeB only after reads
  }
}

extern "C" void kernel_launch(void* const* d_in, const int* in_sizes, int n_in,
                              void* d_out, int out_size, void* d_ws, size_t ws_size,
                              hipStream_t stream) {
  const float* x  = (const float*)d_in[0];
  const float* W1 = (const float*)d_in[1];
  const float* b1 = (const float*)d_in[2];
  const float* W2 = (const float*)d_in[3];
  const float* b2 = (const float*)d_in[4];
  const float* W3 = (const float*)d_in[5];
  const float* b3 = (const float*)d_in[6];
  float* out = (float*)d_out;
  const int B = in_sizes[0] / 17;          // 1048576

  dim3 grid(1024), block(256);             // 4096 waves x 4 super-iterations, 4 blocks/CU
  qmlp_fused<<<grid, block, 0, stream>>>(x, W1, b1, W2, b2, W3, b3, out, B);
}

// Round 12
// 140.331 us; speedup vs baseline: 1.4157x; 1.4157x over previous
//
#include <hip/hip_runtime.h>

// QuantizedActorMLP: x(1M,17) -> quant -> L1(17->64)+quantact -> L2(64->64)+quantact -> L3(64->6)
// Integer-exact bf16 MFMA (ints |n|<=127 exact in bf16, sums < 2^24 exact in fp32 acc).
// R21 == R13 restored (best verified: 138.78/140.57us bench, ~51us/dispatch, absmax 0.0068).
// FINAL-STATE RATIONALE (11 experiments):
//  - Wall = memory service: 92MB at ~1.9TB/s effective (~48us) for this interleaved
//    load+MFMA+store pattern; VALU (~25us SIMD-time) hides underneath. No pipe >50%.
//  - Every escape measured and closed:
//    * request batching/wait-point reduction (R11->R13): flat (not request-bound);
//    * finer tiles + 5 blk/CU (R16): 2.2x regression (stall fraction up);
//    * two-phase split w/ packed intermediate (R15): phase-2 34B-stride scatter 0.46TB/s;
//    * register-staged prefetch (R14/R17/R18/R20): hipcc spills the staging payload
//      under ALL four budget mechanisms (none/min/cap/pinned-range) -> +55-116MB scratch;
//    * occupancy is physically capped at 16 waves/CU by 56 VGPR weight fragments +
//      8.7KB LDS/wave double-buffer -- both diets failed above.
//  Structure: 4-tile supertiles (4352B contiguous) staged via 4x global_load_lds dwordx4
//  + 1x dword (exact, no overflow), double-buffered, ONE s_waitcnt vmcnt(2)/iteration;
//  outputs staged in-place over consumed input LDS; 2 contiguous dwordx4 stores;
//  scalarized wave addressing; integer-exact bf16 MFMA core with K-permuted W2/W3.

typedef __attribute__((ext_vector_type(8))) short short8;    // MFMA A/B frag (8 bf16)
typedef __attribute__((ext_vector_type(4))) float floatx4;   // MFMA C/D frag
typedef __attribute__((ext_vector_type(4))) unsigned int uint4v;
typedef unsigned int uint;

__device__ __forceinline__ uint f32bits(float v) { union { float f; uint u; } c; c.f = v; return c.u; }
__device__ __forceinline__ short bf16i(float v) { return (short)(f32bits(v) >> 16); }
// pack two integer-valued f32 -> two bf16 in one uint (low = z0): one v_perm_b32
__device__ __forceinline__ uint pack2(float z0, float z1) {
  return __builtin_amdgcn_perm(f32bits(z1), f32bits(z0), 0x07060302u);
}
// round-to-nearest-even integer clamped to [-127,127]: v_med3 + v_rndne
__device__ __forceinline__ float qclamp(float v) {
  return __builtin_rintf(__builtin_amdgcn_fmed3f(v, -127.f, 127.f));
}
__device__ __forceinline__ int imin(int a, int b) { return a < b ? a : b; }

// async global->LDS: LDS dest = (uniform) l + lane*size, global src per-lane.
__device__ __forceinline__ void gld16(const float* g, float* l) {
  __builtin_amdgcn_global_load_lds((__attribute__((address_space(1))) void*)(g),
                                   (__attribute__((address_space(3))) void*)(l),
                                   16, 0, 0);
}
__device__ __forceinline__ void gld4(const float* g, float* l) {
  __builtin_amdgcn_global_load_lds((__attribute__((address_space(1))) void*)(g),
                                   (__attribute__((address_space(3))) void*)(l),
                                   4, 0, 0);
}

__global__ void __launch_bounds__(256) qmlp_fused(
    const float* __restrict__ x,
    const float* __restrict__ W1, const float* __restrict__ b1,
    const float* __restrict__ W2, const float* __restrict__ b2,
    const float* __restrict__ W3, const float* __restrict__ b3,
    float* __restrict__ out, int B)
{
  constexpr float QMAXF = 127.0f;
  constexpr float SCALE = 1.33f;
  const float step  = SCALE / QMAXF;
  const float istep = QMAXF / SCALE;

  // One shared pool, two lifetimes:
  //  preamble: wraw1[0..1088) wraw2[1088..5248) wraw3[5248..5638) redv[5638..5650)
  //  main loop: per-wave x double-buffer [w*2176 + d*1088, +1088)  (8704 dw total)
  __shared__ __align__(16) float smem[8704];
  float* wraw1 = smem;            // W1 raw, pitch 17
  float* wraw2 = smem + 1088;     // W2 raw, pitch 65 (pad kills gather conflicts)
  float* wraw3 = smem + 5248;     // W3 raw, pitch 65
  float* redv  = smem + 5638;     // per-wave (m1,m2,m3)

  const int tid  = threadIdx.x;
  const int lane = tid & 63;
  const int bi   = lane & 15;
  const int q    = lane >> 4;
  const int w    = tid >> 6;

  // ---- coalesced staging of raw weights into LDS, max-abs fused into the load ----
  float m1 = 0.f, m2 = 0.f, m3 = 0.f;
  for (int i = tid; i < 272; i += 256) {                       // W1: 1088 floats = 272 float4
    float4 v = ((const float4*)W1)[i];
    ((float4*)wraw1)[i] = v;
    m1 = fmaxf(m1, fmaxf(fmaxf(fabsf(v.x), fabsf(v.y)), fmaxf(fabsf(v.z), fabsf(v.w))));
  }
  for (int i = tid; i < 1024; i += 256) {                      // W2: 4096 floats = 1024 float4
    float4 v = ((const float4*)W2)[i];
    int r = i >> 4, c0 = (i & 15) * 4;                         // no float4 crosses a 64-row
    float* dst = &wraw2[r * 65 + c0];
    dst[0] = v.x; dst[1] = v.y; dst[2] = v.z; dst[3] = v.w;
    m2 = fmaxf(m2, fmaxf(fmaxf(fabsf(v.x), fabsf(v.y)), fmaxf(fabsf(v.z), fabsf(v.w))));
  }
  for (int i = tid; i < 96; i += 256) {                        // W3: 384 floats = 96 float4
    float4 v = ((const float4*)W3)[i];
    int r = i >> 4, c0 = (i & 15) * 4;
    float* dst = &wraw3[r * 65 + c0];
    dst[0] = v.x; dst[1] = v.y; dst[2] = v.z; dst[3] = v.w;
    m3 = fmaxf(m3, fmaxf(fmaxf(fabsf(v.x), fabsf(v.y)), fmaxf(fabsf(v.z), fabsf(v.w))));
  }
  #pragma unroll
  for (int off = 32; off > 0; off >>= 1) {
    m1 = fmaxf(m1, __shfl_down(m1, off));
    m2 = fmaxf(m2, __shfl_down(m2, off));
    m3 = fmaxf(m3, __shfl_down(m3, off));
  }
  if (lane == 0) {
    redv[w * 3 + 0] = m1; redv[w * 3 + 1] = m2; redv[w * 3 + 2] = m3;
  }
  __syncthreads();                 // barrier 1: publishes redv + wraw1/2/3
  float s1 = 0.f, s2 = 0.f, s3 = 0.f;
  #pragma unroll
  for (int i = 0; i < 4; ++i) {
    s1 = fmaxf(s1, redv[i * 3 + 0]);
    s2 = fmaxf(s2, redv[i * 3 + 1]);
    s3 = fmaxf(s3, redv[i * 3 + 2]);
  }
  s1 /= QMAXF; s2 /= QMAXF; s3 /= QMAXF;
  const float rs1 = 1.0f / s1, rs2 = 1.0f / s2, rs3 = 1.0f / s3;

  // ---- weight fragments (integer-valued bf16) from LDS (reciprocal-mul quant) ----
  short8 w1f[4];
  #pragma unroll
  for (int t = 0; t < 4; ++t) {
    #pragma unroll
    for (int j = 0; j < 8; ++j) {
      int k = 8 * q + j;
      float wv = (k < 17) ? wraw1[(16 * t + bi) * 17 + k] : 0.f;
      float wi = fminf(fmaxf(rintf(wv * rs1), -QMAXF), QMAXF);
      w1f[t][j] = bf16i(wi);
    }
  }
  // K-permutation: eta = 32s + 16(j>>2) + 4q + (j&3) so layer-L C/D regs feed layer-(L+1) B-frags.
  short8 w2f[4][2];
  #pragma unroll
  for (int t = 0; t < 4; ++t) {
    #pragma unroll
    for (int s = 0; s < 2; ++s) {
      #pragma unroll
      for (int j = 0; j < 8; ++j) {
        int eta = 32 * s + 16 * (j >> 2) + 4 * q + (j & 3);
        float wv = wraw2[(16 * t + bi) * 65 + eta];
        float wi = fminf(fmaxf(rintf(wv * rs2), -QMAXF), QMAXF);
        w2f[t][s][j] = bf16i(wi);
      }
    }
  }
  short8 w3f[2];
  #pragma unroll
  for (int s = 0; s < 2; ++s) {
    #pragma unroll
    for (int j = 0; j < 8; ++j) {
      int eta = 32 * s + 16 * (j >> 2) + 4 * q + (j & 3);
      float wv = (bi < 6) ? wraw3[bi * 65 + eta] : 0.f;
      float wi = fminf(fmaxf(rintf(wv * rs3), -QMAXF), QMAXF);
      w3f[s][j] = bf16i(wi);
    }
  }

  __syncthreads();                 // barrier 2: weight LDS dead -> safe to reuse for x staging

  // ---- per-slot biases in integer units (few lines each, L2-hot) ----
  const float g1 = (s1 * step) * istep;
  const float g2 = (s2 * step) * istep;
  const float sc3 = s3 * step;
  float b1s[4][4], b2s[4][4], b3s[4];
  #pragma unroll
  for (int t = 0; t < 4; ++t) {
    #pragma unroll
    for (int r = 0; r < 4; ++r) {
      b1s[t][r] = b1[16 * t + 4 * q + r] * istep;
      b2s[t][r] = b2[16 * t + 4 * q + r] * istep;
    }
  }
  #pragma unroll
  for (int r = 0; r < 4; ++r) {
    int n = 4 * q + r;
    b3s[r] = (n < 6) ? b3[n] : 0.f;
  }

  // ---- scalarized work decomposition over 4-tile supertiles ----
  const int ntiles = B >> 4;                                   // 65536
  const int nSup   = ntiles >> 2;                              // 16384 supertiles (64 rows each)
  const int nw     = (int)(gridDim.x << 2);                    // 4096 waves
  const int wid    = __builtin_amdgcn_readfirstlane((int)(blockIdx.x << 2) + w);
  const int nIter  = (nSup + nw - 1) / nw;                     // 4
  const int lastS  = nSup - 1;

  float* xb = smem + w * 2176;                                 // two 1088-dword buffers

  const int lane4 = lane * 4;                                  // dword offsets for staging
  const int fbase = bi * 17 + 8 * q;                           // frag base (q<2)
  const int fb2   = bi * 17 + 16;                              // q==2 single element

  // stage one supertile (1088 dw = 4352B contiguous):
  // 4x dwordx4 (dw 0..1023) + 1x dword (dw 1024..1087: one dword/lane, EXACT, no overflow)
  auto stage = [&](int s, float* buf) {
    const float* tp = x + (size_t)s * 1088;
    gld16(tp + lane4,        buf);                             // dw    0..255
    gld16(tp + 256 + lane4,  buf + 256);                       // dw  256..511
    gld16(tp + 512 + lane4,  buf + 512);                       // dw  512..767
    gld16(tp + 768 + lane4,  buf + 768);                       // dw  768..1023
    gld4 (tp + 1024 + lane,  buf + 1024);                      // dw 1024..1087
  };

  const floatx4 zero4 = {0.f, 0.f, 0.f, 0.f};

  // ---- prologue: fill buffer 0 ----
  stage(imin(wid, lastS), xb);

  #pragma unroll 1
  for (int it = 0; it < nIter; ++it) {
    const int gs = imin(wid + it * nw, lastS);
    float* cur = xb + (it & 1) * 1088;

    // retire this buffer's 5 loads; allow last iter's 2 stores to stay outstanding
    if (it == 0) { asm volatile("s_waitcnt vmcnt(0)" ::: "memory"); }
    else         { asm volatile("s_waitcnt vmcnt(2)" ::: "memory"); }

    // issue next supertile into the other buffer (its old contents are fully consumed)
    if (it + 1 < nIter) stage(imin(wid + (it + 1) * nw, lastS), xb + ((it + 1) & 1) * 1088);

    #pragma unroll 1
    for (int k = 0; k < 4; ++k) {
      float* tb = cur + k * 272;

      // fragment gather from LDS (stride-17-dword: max 2-way bank alias = free)
      float xr[8];
      if (q < 2) {
        #pragma unroll
        for (int j = 0; j < 8; ++j) xr[j] = tb[fbase + j];
      } else if (q == 2) {
        xr[0] = tb[fb2];
        #pragma unroll
        for (int j = 1; j < 8; ++j) xr[j] = 0.f;
      } else {
        #pragma unroll
        for (int j = 0; j < 8; ++j) xr[j] = 0.f;
      }

      // input quant -> B-frag: lane holds Xq[row=bi][k=8q+j]
      uint4v ap;
      #pragma unroll
      for (int jp = 0; jp < 4; ++jp)
        ap[jp] = pack2(qclamp(xr[2 * jp] * istep), qclamp(xr[2 * jp + 1] * istep));
      short8 af = __builtin_bit_cast(short8, ap);

      // L1
      floatx4 c1[4];
      #pragma unroll
      for (int t = 0; t < 4; ++t)
        c1[t] = __builtin_amdgcn_mfma_f32_16x16x32_bf16(w1f[t], af, zero4, 0, 0, 0);

      uint4v h1u[2];
      #pragma unroll
      for (int t = 0; t < 4; ++t) {
        float z0 = qclamp(fmaf(c1[t][0], g1, b1s[t][0]));
        float z1 = qclamp(fmaf(c1[t][1], g1, b1s[t][1]));
        float z2 = qclamp(fmaf(c1[t][2], g1, b1s[t][2]));
        float z3 = qclamp(fmaf(c1[t][3], g1, b1s[t][3]));
        h1u[t >> 1][(t & 1) * 2 + 0] = pack2(z0, z1);
        h1u[t >> 1][(t & 1) * 2 + 1] = pack2(z2, z3);
      }
      short8 h1a = __builtin_bit_cast(short8, h1u[0]);
      short8 h1b = __builtin_bit_cast(short8, h1u[1]);

      // L2 (K=64)
      floatx4 c2[4];
      #pragma unroll
      for (int t = 0; t < 4; ++t) {
        c2[t] = __builtin_amdgcn_mfma_f32_16x16x32_bf16(w2f[t][0], h1a, zero4, 0, 0, 0);
        c2[t] = __builtin_amdgcn_mfma_f32_16x16x32_bf16(w2f[t][1], h1b, c2[t], 0, 0, 0);
      }

      uint4v h2u[2];
      #pragma unroll
      for (int t = 0; t < 4; ++t) {
        float z0 = qclamp(fmaf(c2[t][0], g2, b2s[t][0]));
        float z1 = qclamp(fmaf(c2[t][1], g2, b2s[t][1]));
        float z2 = qclamp(fmaf(c2[t][2], g2, b2s[t][2]));
        float z3 = qclamp(fmaf(c2[t][3], g2, b2s[t][3]));
        h2u[t >> 1][(t & 1) * 2 + 0] = pack2(z0, z1);
        h2u[t >> 1][(t & 1) * 2 + 1] = pack2(z2, z3);
      }
      short8 h2a = __builtin_bit_cast(short8, h2u[0]);
      short8 h2b = __builtin_bit_cast(short8, h2u[1]);

      // L3
      floatx4 c3;
      c3 = __builtin_amdgcn_mfma_f32_16x16x32_bf16(w3f[0], h2a, zero4, 0, 0, 0);
      c3 = __builtin_amdgcn_mfma_f32_16x16x32_bf16(w3f[1], h2b, c3, 0, 0, 0);

      float o0 = fmaf(c3[0], sc3, b3s[0]);
      float o1 = fmaf(c3[1], sc3, b3s[1]);
      float o2 = fmaf(c3[2], sc3, b3s[2]);
      float o3 = fmaf(c3[3], sc3, b3s[3]);

      // stage tile-k output IN-PLACE at cur[k*96]: audited -- every write lands on input
      // already consumed in program order. ds_write_b64, 24B stride.
      float* ob = cur + k * 96;
      if (q == 0) {
        *(float2*)(ob + bi * 6)     = make_float2(o0, o1);
        *(float2*)(ob + bi * 6 + 2) = make_float2(o2, o3);
      } else if (q == 1) {
        *(float2*)(ob + bi * 6 + 4) = make_float2(o0, o1);
      }
    }

    asm volatile("" ::: "memory");                             // pin LDS write->read order
    // batched store of 64 rows x 6 = 384 dw = 1536B contiguous: 2 dwordx4 stores
    {
      float4 v0 = *(const float4*)(cur + lane4);               // dw 0..255
      *(float4*)(out + (size_t)gs * 384 + lane4) = v0;
      if (lane < 32) {
        float4 v1 = *(const float4*)(cur + 256 + lane4);       // dw 256..383
        *(float4*)(out + (size_t)gs * 384 + 256 + lane4) = v1;
      }
    }
  }
}

extern "C" void kernel_launch(void* const* d_in, const int* in_sizes, int n_in,
                              void* d_out, int out_size, void* d_ws, size_t ws_size,
                              hipStream_t stream) {
  const float* x  = (const float*)d_in[0];
  const float* W1 = (const float*)d_in[1];
  const float* b1 = (const float*)d_in[2];
  const float* W2 = (const float*)d_in[3];
  const float* b2 = (const float*)d_in[4];
  const float* W3 = (const float*)d_in[5];
  const float* b3 = (const float*)d_in[6];
  float* out = (float*)d_out;
  const int B = in_sizes[0] / 17;          // 1048576

  dim3 grid(1024), block(256);             // 4096 waves x 4 super-iterations, 4 blocks/CU
  qmlp_fused<<<grid, block, 0, stream>>>(x, W1, b1, W2, b2, W3, b3, out, B);
}